// Round 8
// baseline (708.832 us; speedup 1.0000x reference)
//
#include <hip/hip_runtime.h>
#include <hip/hip_bf16.h>

#define D 512

typedef __attribute__((ext_vector_type(8))) short bf16x8;
typedef __attribute__((ext_vector_type(4))) float f32x4;

__device__ inline float b2f(short h) {
    union { unsigned u; float f; } c;
    c.u = ((unsigned)(unsigned short)h) << 16;
    return c.f;
}

__device__ __forceinline__ void stage16(const void* g, void* l) {
    __builtin_amdgcn_global_load_lds((const __attribute__((address_space(1))) void*)g,
                                     (__attribute__((address_space(3))) void*)l, 16, 0, 0);
}

// ---------------- degree histograms ----------------
__global__ void k_hist(const int* __restrict__ src, const int* __restrict__ dst,
                       int* __restrict__ deg_out, int* __restrict__ deg_in, int E) {
    int e = blockIdx.x * 256 + threadIdx.x;
    if (e < E) {
        atomicAdd(&deg_out[src[e]], 1);
        atomicAdd(&deg_in[dst[e]], 1);
    }
}

// ---------------- pre-scale x by rsqrt(deg_out) -> bf16 xs ----------------
__global__ __launch_bounds__(256)
void k_scale(const float* __restrict__ x, const int* __restrict__ deg_out,
             __hip_bfloat16* __restrict__ xs, int total16) {
    int i = blockIdx.x * 256 + threadIdx.x;   // one thread = 8 elements
    if (i >= total16) return;
    int node = i >> 6;
    float w = rsqrtf((float)max(deg_out[node], 1));
    const float4* p = (const float4*)(x + (size_t)i * 8);
    float4 a = p[0], b = p[1];
    union { float4 f4; __hip_bfloat16 h[8]; } o;
    o.h[0] = __float2bfloat16(a.x * w);
    o.h[1] = __float2bfloat16(a.y * w);
    o.h[2] = __float2bfloat16(a.z * w);
    o.h[3] = __float2bfloat16(a.w * w);
    o.h[4] = __float2bfloat16(b.x * w);
    o.h[5] = __float2bfloat16(b.y * w);
    o.h[6] = __float2bfloat16(b.z * w);
    o.h[7] = __float2bfloat16(b.w * w);
    *(float4*)(xs + (size_t)i * 8) = o.f4;
}

// ---------------- exclusive scan of deg_in -> row_start ----------------
__global__ void k_scan1(const int* __restrict__ deg_in, int* __restrict__ row_start,
                        int* __restrict__ partials, int N) {
    __shared__ int sm[1024];
    int tid = threadIdx.x;
    int i = blockIdx.x * 1024 + tid;
    int v = (i < N) ? deg_in[i] : 0;
    sm[tid] = v;
    __syncthreads();
    int acc = v;
    #pragma unroll
    for (int off = 1; off < 1024; off <<= 1) {
        int t = (tid >= off) ? sm[tid - off] : 0;
        __syncthreads();
        acc += t;
        sm[tid] = acc;
        __syncthreads();
    }
    if (i < N) row_start[i] = acc - v;
    if (tid == 1023) partials[blockIdx.x] = acc;
}

__global__ void k_scan2w(int* __restrict__ partials, int* __restrict__ row_start,
                         int nb, int N) {
    int lane = threadIdx.x;
    int orig = (lane < nb) ? partials[lane] : 0;
    int v = orig;
    #pragma unroll
    for (int off = 1; off < 64; off <<= 1) {
        int t = __shfl_up(v, off, 64);
        if (lane >= off) v += t;
    }
    if (lane < nb) partials[lane] = v - orig;
    if (lane == 63) row_start[N] = v;
}

__global__ void k_scan2s(int* __restrict__ partials, int* __restrict__ row_start,
                         int nb, int N) {
    if (threadIdx.x == 0 && blockIdx.x == 0) {
        int run = 0;
        for (int b = 0; b < nb; b++) { int t = partials[b]; partials[b] = run; run += t; }
        row_start[N] = run;
    }
}

__global__ void k_scan3(int* __restrict__ row_start, const int* __restrict__ partials, int N) {
    int i = blockIdx.x * 256 + threadIdx.x;
    if (i < N) row_start[i] += partials[i >> 10];
}

// ---------------- CSR bucket fill ----------------
__global__ void k_fill(const int* __restrict__ src, const int* __restrict__ dst,
                       const int* __restrict__ row_start, int* __restrict__ cursor,
                       int* __restrict__ csr_src, int E) {
    int e = blockIdx.x * 256 + threadIdx.x;
    if (e < E) {
        int d = dst[e];
        int slot = atomicAdd(&cursor[d], 1);
        csr_src[row_start[d] + slot] = src[e];
    }
}

// ---------------- SpMM over bf16 pre-scaled rows (row-major A, coalesced) ----------------
__global__ __launch_bounds__(256)
void k_spmm(const __hip_bfloat16* __restrict__ xs, const int* __restrict__ row_start,
            const int* __restrict__ csr_src, __hip_bfloat16* __restrict__ A, int N) {
    int wid = threadIdx.x >> 6;
    int lane = threadIdx.x & 63;
    int node = blockIdx.x * 4 + wid;
    if (node >= N) return;
    int rs = row_start[node], re = row_start[node + 1];

    float acc[8];
    #pragma unroll
    for (int k = 0; k < 8; k++) acc[k] = 0.f;
    const __hip_bfloat16* xl = xs + (size_t)lane * 8;

    int j = rs;
    for (; j + 4 <= re; j += 4) {
        int s0 = csr_src[j], s1 = csr_src[j + 1], s2 = csr_src[j + 2], s3 = csr_src[j + 3];
        bf16x8 v0 = *(const bf16x8*)(xl + (size_t)s0 * D);
        bf16x8 v1 = *(const bf16x8*)(xl + (size_t)s1 * D);
        bf16x8 v2 = *(const bf16x8*)(xl + (size_t)s2 * D);
        bf16x8 v3 = *(const bf16x8*)(xl + (size_t)s3 * D);
        #pragma unroll
        for (int k = 0; k < 8; k++)
            acc[k] += (b2f(v0[k]) + b2f(v1[k])) + (b2f(v2[k]) + b2f(v3[k]));
    }
    for (; j < re; j++) {
        int s = csr_src[j];
        bf16x8 v = *(const bf16x8*)(xl + (size_t)s * D);
        #pragma unroll
        for (int k = 0; k < 8; k++) acc[k] += b2f(v[k]);
    }

    float rn = rsqrtf((float)max(re - rs, 1));
    union { float4 f4; __hip_bfloat16 h[8]; } o;
    #pragma unroll
    for (int k = 0; k < 8; k++) o.h[k] = __float2bfloat16(acc[k] * rn);
    *(float4*)(A + (size_t)node * D + lane * 8) = o.f4;
}

// ---------------- f32 fallback SpMM ----------------
__global__ __launch_bounds__(256)
void k_spmm_f32(const float* __restrict__ x, const int* __restrict__ row_start,
                const int* __restrict__ csr_src, const int* __restrict__ deg_out,
                __hip_bfloat16* __restrict__ A, int N) {
    int wid = threadIdx.x >> 6;
    int lane = threadIdx.x & 63;
    int node = blockIdx.x * 4 + wid;
    if (node >= N) return;
    int rs = row_start[node], re = row_start[node + 1];
    float4 acc0 = {0.f, 0.f, 0.f, 0.f};
    float4 acc1 = {0.f, 0.f, 0.f, 0.f};
    const float* xl = x + (size_t)lane * 8;
    for (int j = rs; j < re; j++) {
        int s = csr_src[j];
        float w = rsqrtf((float)max(deg_out[s], 1));
        const float4* p = (const float4*)(xl + (size_t)s * D);
        float4 a = p[0], b = p[1];
        acc0.x += a.x * w; acc0.y += a.y * w; acc0.z += a.z * w; acc0.w += a.w * w;
        acc1.x += b.x * w; acc1.y += b.y * w; acc1.z += b.z * w; acc1.w += b.w * w;
    }
    float rn = rsqrtf((float)max(re - rs, 1));
    union { float4 f4; __hip_bfloat16 h[8]; } o;
    o.h[0] = __float2bfloat16(acc0.x * rn);
    o.h[1] = __float2bfloat16(acc0.y * rn);
    o.h[2] = __float2bfloat16(acc0.z * rn);
    o.h[3] = __float2bfloat16(acc0.w * rn);
    o.h[4] = __float2bfloat16(acc1.x * rn);
    o.h[5] = __float2bfloat16(acc1.y * rn);
    o.h[6] = __float2bfloat16(acc1.z * rn);
    o.h[7] = __float2bfloat16(acc1.w * rn);
    *(float4*)(A + (size_t)node * D + lane * 8) = o.f4;
}

// ---------------- pack W into per-col-chunk MFMA B layout ----------------
// bid = c*128 + kt*8 + ntc ; element (bid, lane, j) =
//   W[kt*32 + (lane>>4)*8 + j][(c*8 + ntc)*16 + (lane&15)]
// => chunk c is a contiguous 128KB block; frag (kt,t) at offset (kt*8+t)*1024.
__global__ void k_packw2(const float* __restrict__ W, __hip_bfloat16* __restrict__ Wp) {
    int bid = blockIdx.x;        // 0..511
    int c = bid >> 7, kt = (bid >> 3) & 15, ntc = bid & 7;
    int lane = threadIdx.x;      // 0..63
    int k0 = kt * 32 + (lane >> 4) * 8;
    int n  = (c * 8 + ntc) * 16 + (lane & 15);
    union { float4 f4; __hip_bfloat16 h[8]; } o;
    #pragma unroll
    for (int j = 0; j < 8; j++)
        o.h[j] = __float2bfloat16(W[(size_t)(k0 + j) * D + n]);
    *(float4*)(Wp + ((size_t)bid * 64 + lane) * 8) = o.f4;
}

// legacy pack (fallback path)
__global__ void k_packw(const float* __restrict__ W, __hip_bfloat16* __restrict__ Wp) {
    int tile = blockIdx.x;
    int lane = threadIdx.x;
    int kt = tile >> 5, nt = tile & 31;
    int k0 = kt * 32 + (lane >> 4) * 8;
    int n  = nt * 16 + (lane & 15);
    union { float4 f4; __hip_bfloat16 h[8]; } o;
    #pragma unroll
    for (int j = 0; j < 8; j++)
        o.h[j] = __float2bfloat16(W[(size_t)(k0 + j) * D + n]);
    *(float4*)(Wp + ((size_t)tile * 64 + lane) * 8) = o.f4;
}

// ---------------- pass A: W-stationary GEMM, h = A@W (bf16; bias deferred to LN) ----
// grid = 256 blocks: cch = bid&3 (128-col chunk), bstrip = bid>>2 (0..63).
// Block = 1024 thr = 16 waves; W chunk (128KB) staged to LDS ONCE (single barrier).
// Each wave owns 16 rows x 128 cols per strip: per kt = 1 global A-load (no dup)
// + 8 conflict-free ds_reads + 8 MFMA. No K-loop barriers; grid-strides 256-row strips.
__global__ __launch_bounds__(1024, 1)
void k_gemm5(const __hip_bfloat16* __restrict__ A, const __hip_bfloat16* __restrict__ Wp,
             __hip_bfloat16* __restrict__ h, int M) {
    __shared__ __align__(16) char ldsW[131072];

    int tid = threadIdx.x;
    int wid = tid >> 6, lane = tid & 63;
    int l4 = lane >> 4, coll = lane & 15;
    int cch = blockIdx.x & 3;
    int bstrip = blockIdx.x >> 2;    // 0..63

    // stage W chunk: 8 rounds x 1024 thr x 16B = 128KB
    {
        const char* g = (const char*)Wp + (size_t)cch * 131072 + (size_t)wid * 1024 + (size_t)lane * 16;
        char* l = ldsW + wid * 1024;
        #pragma unroll
        for (int r = 0; r < 8; r++)
            stage16(g + r * 16384, l + r * 16384);
    }
    asm volatile("s_waitcnt vmcnt(0)" ::: "memory");
    __builtin_amdgcn_sched_barrier(0);
    __builtin_amdgcn_s_barrier();

    for (int sb = bstrip; ; sb += 64) {
        int row_base = sb * 256;            // 16 waves x 16 rows
        if (row_base >= M) break;
        int ar = row_base + wid * 16 + coll;
        if (ar > M - 1) ar = M - 1;         // clamp: dup rows write identical h values
        const char* ap = (const char*)A + (size_t)ar * 1024 + l4 * 16;

        f32x4 acc[8];
        #pragma unroll
        for (int t = 0; t < 8; t++) acc[t] = (f32x4){0.f, 0.f, 0.f, 0.f};

        for (int kt = 0; kt < 16; kt++) {
            bf16x8 af = *(const bf16x8*)(ap + (size_t)kt * 64);
            const char* wk = ldsW + (size_t)kt * 8192 + (size_t)lane * 16;
            #pragma unroll
            for (int t = 0; t < 8; t++) {
                bf16x8 bf = *(const bf16x8*)(wk + (size_t)t * 1024);
                acc[t] = __builtin_amdgcn_mfma_f32_16x16x32_bf16(af, bf, acc[t], 0, 0, 0);
            }
        }

        // store h tile: row = row_base + wid*16 + l4*4 + r; col = cch*128 + t*16 + coll
        int rowb = row_base + wid * 16 + l4 * 4;
        #pragma unroll
        for (int r = 0; r < 4; r++) {
            int row = rowb + r;
            if (row < M) {
                __hip_bfloat16* hrow = h + (size_t)row * D + cch * 128 + coll;
                #pragma unroll
                for (int t = 0; t < 8; t++)
                    hrow[t * 16] = __float2bfloat16(acc[t][r]);
            }
        }
    }
}

// ---------------- pass B: bias + LayerNorm + tanh-GELU (one wave per row) ----------------
__global__ __launch_bounds__(256)
void k_lngelu(const __hip_bfloat16* __restrict__ h, const float* __restrict__ bias,
              const float* __restrict__ gamma, const float* __restrict__ beta,
              float* __restrict__ out, int M) {
    int gw = (blockIdx.x * 256 + threadIdx.x) >> 6;
    int lane = threadIdx.x & 63;
    int nw = (gridDim.x * 256) >> 6;

    float g8[8], b8[8], bi8[8];
    #pragma unroll
    for (int k = 0; k < 8; k++) {
        g8[k] = gamma[lane * 8 + k];
        b8[k] = beta[lane * 8 + k];
        bi8[k] = bias[lane * 8 + k];
    }

    for (int row = gw; row < M; row += nw) {
        bf16x8 v = *(const bf16x8*)(h + (size_t)row * D + lane * 8);
        float f[8];
        float s = 0.f, q = 0.f;
        #pragma unroll
        for (int k = 0; k < 8; k++) {
            f[k] = b2f(v[k]) + bi8[k];
            s += f[k]; q += f[k] * f[k];
        }
        #pragma unroll
        for (int off = 1; off < 64; off <<= 1) {
            s += __shfl_xor(s, off, 64);
            q += __shfl_xor(q, off, 64);
        }
        float mean = s * (1.0f / 512.0f);
        float var = q * (1.0f / 512.0f) - mean * mean;
        float rstd = rsqrtf(fmaxf(var, 0.f) + 1e-5f);
        float o[8];
        #pragma unroll
        for (int k = 0; k < 8; k++) {
            float y = (f[k] - mean) * rstd * g8[k] + b8[k];
            float yy = y * y;
            float pz = fmaf(yy, -0.1029423374f, -2.3022076728f);
            float e = __builtin_amdgcn_exp2f(y * pz);
            o[k] = y * __builtin_amdgcn_rcpf(1.0f + e);
        }
        float* orow = out + (size_t)row * D + lane * 8;
        *(float4*)orow = (float4){o[0], o[1], o[2], o[3]};
        *(float4*)(orow + 4) = (float4){o[4], o[5], o[6], o[7]};
    }
}

// ---------------- legacy fused GEMM (fallback if ws too small) ----------------
__global__ __launch_bounds__(512)
void k_gemm(const __hip_bfloat16* __restrict__ A, const __hip_bfloat16* __restrict__ Wp,
            const float* __restrict__ bias, const float* __restrict__ gamma,
            const float* __restrict__ beta, float* __restrict__ out, int M) {
    int tid = threadIdx.x;
    int wid = tid >> 6, lane = tid & 63;
    int wm = wid >> 2;
    int wn = wid & 3;
    int l4 = lane >> 4, coll = lane & 15;
    int m0 = blockIdx.x * 32 + wm * 16;
    int arow = m0 + coll;
    bool rowok = (arow < M);

    f32x4 acc[8];
    #pragma unroll
    for (int t = 0; t < 8; t++) acc[t] = (f32x4){0.f, 0.f, 0.f, 0.f};

    const bf16x8* wpb = (const bf16x8*)Wp;
    for (int kt = 0; kt < 16; kt++) {
        bf16x8 afrag;
        if (rowok) afrag = *(const bf16x8*)(A + (size_t)arow * D + kt * 32 + l4 * 8);
        else afrag = (bf16x8){0,0,0,0,0,0,0,0};
        const bf16x8* wp = wpb + ((size_t)(kt * 32 + wn * 8) * 64 + lane);
        #pragma unroll
        for (int t = 0; t < 8; t++) {
            bf16x8 bfrag = wp[(size_t)t * 64];
            acc[t] = __builtin_amdgcn_mfma_f32_16x16x32_bf16(afrag, bfrag, acc[t], 0, 0, 0);
        }
    }
    __shared__ float s_sum[32][4];
    __shared__ float s_sq[32][4];
    #pragma unroll
    for (int r = 0; r < 4; r++) {
        float s = 0.f, q = 0.f;
        #pragma unroll
        for (int t = 0; t < 8; t++) {
            int col = wn * 128 + t * 16 + coll;
            float v = acc[t][r] + bias[col];
            acc[t][r] = v;
            s += v; q += v * v;
        }
        #pragma unroll
        for (int off = 1; off < 16; off <<= 1) {
            s += __shfl_xor(s, off, 64);
            q += __shfl_xor(q, off, 64);
        }
        if (coll == 0) {
            int rb = wm * 16 + l4 * 4 + r;
            s_sum[rb][wn] = s;
            s_sq[rb][wn] = q;
        }
    }
    __syncthreads();
    #pragma unroll
    for (int r = 0; r < 4; r++) {
        int rb = wm * 16 + l4 * 4 + r;
        int gr = blockIdx.x * 32 + rb;
        if (gr >= M) continue;
        float s = s_sum[rb][0] + s_sum[rb][1] + s_sum[rb][2] + s_sum[rb][3];
        float q = s_sq[rb][0] + s_sq[rb][1] + s_sq[rb][2] + s_sq[rb][3];
        float mean = s * (1.0f / 512.0f);
        float var = q * (1.0f / 512.0f) - mean * mean;
        float rstd = rsqrtf(fmaxf(var, 0.f) + 1e-5f);
        #pragma unroll
        for (int t = 0; t < 8; t++) {
            int col = wn * 128 + t * 16 + coll;
            float y = (acc[t][r] - mean) * rstd * gamma[col] + beta[col];
            float yy = y * y;
            float pz = fmaf(yy, -0.1029423374f, -2.3022076728f);
            float e = __builtin_amdgcn_exp2f(y * pz);
            out[(size_t)gr * D + col] = y * __builtin_amdgcn_rcpf(1.0f + e);
        }
    }
}

extern "C" void kernel_launch(void* const* d_in, const int* in_sizes, int n_in,
                              void* d_out, int out_size, void* d_ws, size_t ws_size,
                              hipStream_t stream) {
    const float* x     = (const float*)d_in[0];
    const float* W     = (const float*)d_in[1];
    const float* b     = (const float*)d_in[2];
    const float* gamma = (const float*)d_in[3];
    const float* beta  = (const float*)d_in[4];
    const int*   src   = (const int*)d_in[5];
    const int*   dst   = (const int*)d_in[6];
    int N = in_sizes[0] / D;
    int E = in_sizes[5];
    float* out = (float*)d_out;

    int* deg_out   = (int*)d_ws;                 // N
    int* deg_in    = deg_out + N;                // N
    int* row_start = deg_in + N;                 // N+1
    int* cursor    = row_start + N + 1;          // N
    int* partials  = cursor + N;                 // <=64
    int* csr_src   = partials + 64;              // E
    uintptr_t p = (uintptr_t)(csr_src + E);
    p = (p + 255) & ~(uintptr_t)255;
    __hip_bfloat16* A = (__hip_bfloat16*)p;      // N*D bf16 row-major
    p += (size_t)N * D * sizeof(__hip_bfloat16);
    p = (p + 255) & ~(uintptr_t)255;
    __hip_bfloat16* Wp = (__hip_bfloat16*)p;     // D*D bf16
    p += (size_t)D * D * sizeof(__hip_bfloat16);
    p = (p + 255) & ~(uintptr_t)255;
    __hip_bfloat16* xs = (__hip_bfloat16*)p;     // N*D bf16 (xs, later reused as h)
    size_t need_xs = (p - (uintptr_t)d_ws) + (size_t)N * D * sizeof(__hip_bfloat16);
    bool use_bf16_path = (ws_size >= need_xs);

    hipMemsetAsync(deg_out, 0, (size_t)2 * N * sizeof(int), stream);
    hipMemsetAsync(cursor, 0, (size_t)N * sizeof(int), stream);

    k_hist<<<(E + 255) / 256, 256, 0, stream>>>(src, dst, deg_out, deg_in, E);
    int nb1 = (N + 1023) / 1024;
    k_scan1<<<nb1, 1024, 0, stream>>>(deg_in, row_start, partials, N);
    if (nb1 <= 64)
        k_scan2w<<<1, 64, 0, stream>>>(partials, row_start, nb1, N);
    else
        k_scan2s<<<1, 64, 0, stream>>>(partials, row_start, nb1, N);
    k_scan3<<<(N + 255) / 256, 256, 0, stream>>>(row_start, partials, N);
    k_fill<<<(E + 255) / 256, 256, 0, stream>>>(src, dst, row_start, cursor, csr_src, E);

    if (use_bf16_path) {
        int total16 = N * 64;
        k_scale<<<(total16 + 255) / 256, 256, 0, stream>>>(x, deg_out, xs, total16);
        k_spmm<<<(N + 3) / 4, 256, 0, stream>>>(xs, row_start, csr_src, A, N);
        k_packw2<<<512, 64, 0, stream>>>(W, Wp);
        __hip_bfloat16* h = xs;   // xs dead after k_spmm; reuse as h
        k_gemm5<<<256, 1024, 0, stream>>>(A, Wp, h, N);
        k_lngelu<<<1024, 256, 0, stream>>>(h, b, gamma, beta, out, N);
    } else {
        k_spmm_f32<<<(N + 3) / 4, 256, 0, stream>>>(x, row_start, csr_src, deg_out, A, N);
        k_packw<<<512, 64, 0, stream>>>(W, Wp);
        k_gemm<<<(N + 31) / 32, 512, 0, stream>>>(A, Wp, b, gamma, beta, out, N);
    }
}

// Round 9
// 291.410 us; speedup vs baseline: 2.4324x; 2.4324x over previous
//
#include <hip/hip_runtime.h>
#include <hip/hip_bf16.h>

#define D 512

typedef __attribute__((ext_vector_type(8))) short bf16x8;
typedef __attribute__((ext_vector_type(4))) float f32x4;

__device__ inline float b2f(short h) {
    union { unsigned u; float f; } c;
    c.u = ((unsigned)(unsigned short)h) << 16;
    return c.f;
}

// ---------------- degree histograms ----------------
__global__ void k_hist(const int* __restrict__ src, const int* __restrict__ dst,
                       int* __restrict__ deg_out, int* __restrict__ deg_in, int E) {
    int e = blockIdx.x * 256 + threadIdx.x;
    if (e < E) {
        atomicAdd(&deg_out[src[e]], 1);
        atomicAdd(&deg_in[dst[e]], 1);
    }
}

// ---------------- pre-scale x by rsqrt(deg_out) -> bf16 xs ----------------
__global__ __launch_bounds__(256)
void k_scale(const float* __restrict__ x, const int* __restrict__ deg_out,
             __hip_bfloat16* __restrict__ xs, int total16) {
    int i = blockIdx.x * 256 + threadIdx.x;   // one thread = 8 elements
    if (i >= total16) return;
    int node = i >> 6;
    float w = rsqrtf((float)max(deg_out[node], 1));
    const float4* p = (const float4*)(x + (size_t)i * 8);
    float4 a = p[0], b = p[1];
    union { float4 f4; __hip_bfloat16 h[8]; } o;
    o.h[0] = __float2bfloat16(a.x * w);
    o.h[1] = __float2bfloat16(a.y * w);
    o.h[2] = __float2bfloat16(a.z * w);
    o.h[3] = __float2bfloat16(a.w * w);
    o.h[4] = __float2bfloat16(b.x * w);
    o.h[5] = __float2bfloat16(b.y * w);
    o.h[6] = __float2bfloat16(b.z * w);
    o.h[7] = __float2bfloat16(b.w * w);
    *(float4*)(xs + (size_t)i * 8) = o.f4;
}

// ---------------- exclusive scan of deg_in -> row_start ----------------
__global__ void k_scan1(const int* __restrict__ deg_in, int* __restrict__ row_start,
                        int* __restrict__ partials, int N) {
    __shared__ int sm[1024];
    int tid = threadIdx.x;
    int i = blockIdx.x * 1024 + tid;
    int v = (i < N) ? deg_in[i] : 0;
    sm[tid] = v;
    __syncthreads();
    int acc = v;
    #pragma unroll
    for (int off = 1; off < 1024; off <<= 1) {
        int t = (tid >= off) ? sm[tid - off] : 0;
        __syncthreads();
        acc += t;
        sm[tid] = acc;
        __syncthreads();
    }
    if (i < N) row_start[i] = acc - v;
    if (tid == 1023) partials[blockIdx.x] = acc;
}

__global__ void k_scan2w(int* __restrict__ partials, int* __restrict__ row_start,
                         int nb, int N) {
    int lane = threadIdx.x;
    int orig = (lane < nb) ? partials[lane] : 0;
    int v = orig;
    #pragma unroll
    for (int off = 1; off < 64; off <<= 1) {
        int t = __shfl_up(v, off, 64);
        if (lane >= off) v += t;
    }
    if (lane < nb) partials[lane] = v - orig;
    if (lane == 63) row_start[N] = v;
}

__global__ void k_scan2s(int* __restrict__ partials, int* __restrict__ row_start,
                         int nb, int N) {
    if (threadIdx.x == 0 && blockIdx.x == 0) {
        int run = 0;
        for (int b = 0; b < nb; b++) { int t = partials[b]; partials[b] = run; run += t; }
        row_start[N] = run;
    }
}

__global__ void k_scan3(int* __restrict__ row_start, const int* __restrict__ partials, int N) {
    int i = blockIdx.x * 256 + threadIdx.x;
    if (i < N) row_start[i] += partials[i >> 10];
}

// ---------------- CSR bucket fill ----------------
__global__ void k_fill(const int* __restrict__ src, const int* __restrict__ dst,
                       const int* __restrict__ row_start, int* __restrict__ cursor,
                       int* __restrict__ csr_src, int E) {
    int e = blockIdx.x * 256 + threadIdx.x;
    if (e < E) {
        int d = dst[e];
        int slot = atomicAdd(&cursor[d], 1);
        csr_src[row_start[d] + slot] = src[e];
    }
}

// ---------------- pack W into per-col-chunk MFMA B layout ----------------
// bid = c*128 + kt*8 + ntc ; element (bid, lane, j) =
//   W[kt*32 + (lane>>4)*8 + j][(c*8 + ntc)*16 + (lane&15)]
// => chunk c contiguous 128KB; frag (kt,t) at byte (kt*8+t)*1024 within chunk.
__global__ void k_packw2(const float* __restrict__ W, __hip_bfloat16* __restrict__ Wp) {
    int bid = blockIdx.x;        // 0..511
    int c = bid >> 7, kt = (bid >> 3) & 15, ntc = bid & 7;
    int lane = threadIdx.x;      // 0..63
    int k0 = kt * 32 + (lane >> 4) * 8;
    int n  = (c * 8 + ntc) * 16 + (lane & 15);
    union { float4 f4; __hip_bfloat16 h[8]; } o;
    #pragma unroll
    for (int j = 0; j < 8; j++)
        o.h[j] = __float2bfloat16(W[(size_t)(k0 + j) * D + n]);
    *(float4*)(Wp + ((size_t)bid * 64 + lane) * 8) = o.f4;
}

// ---------------- FUSED: SpMM-gather -> LDS A-tile -> GEMM + bias + LN + GELU ----------------
// 512 thr = 8 waves; block = 64 nodes x 512 cols.
// Phase 1: wave w gathers nodes tb+w*8..tb+w*8+7 (spmm inner loop), writes bf16 rows
//   into XOR-swizzled LDS tile (byte granule ^= (row&7)<<4 -> conflict-free frag reads).
// Phase 2 (one barrier): gemm3 structure - A-frags from LDS, B-frags register-direct
//   from L2-resident packed Wp (8 per wave per kt), 16 MFMA/kt, LN+GELU epilogue.
__global__ __launch_bounds__(512, 2)
void k_fused(const __hip_bfloat16* __restrict__ xs, const int* __restrict__ row_start,
             const int* __restrict__ csr_src, const __hip_bfloat16* __restrict__ Wp,
             const float* __restrict__ bias, const float* __restrict__ gamma,
             const float* __restrict__ beta, float* __restrict__ out, int M) {
    __shared__ __align__(16) char ldsA[65536];   // 64 rows x 1KB, swizzled
    __shared__ float s_sum[64][4];
    __shared__ float s_sq[64][4];

    int tid = threadIdx.x;
    int wid = tid >> 6, lane = tid & 63;
    int l4 = lane >> 4, coll = lane & 15;
    int tb = blockIdx.x * 64;

    // ---- phase 1: gather 8 nodes per wave ----
    {
        const __hip_bfloat16* xl = xs + (size_t)lane * 8;
        for (int i = 0; i < 8; i++) {
            int rowt = wid * 8 + i;
            int node = tb + rowt;
            char* dst = ldsA + rowt * 1024 + ((lane * 16) ^ ((rowt & 7) << 4));
            if (node < M) {
                int rs = row_start[node], re = row_start[node + 1];
                float acc[8];
                #pragma unroll
                for (int k = 0; k < 8; k++) acc[k] = 0.f;
                int j = rs;
                for (; j + 4 <= re; j += 4) {
                    int s0 = csr_src[j], s1 = csr_src[j + 1], s2 = csr_src[j + 2], s3 = csr_src[j + 3];
                    bf16x8 v0 = *(const bf16x8*)(xl + (size_t)s0 * D);
                    bf16x8 v1 = *(const bf16x8*)(xl + (size_t)s1 * D);
                    bf16x8 v2 = *(const bf16x8*)(xl + (size_t)s2 * D);
                    bf16x8 v3 = *(const bf16x8*)(xl + (size_t)s3 * D);
                    #pragma unroll
                    for (int k = 0; k < 8; k++)
                        acc[k] += (b2f(v0[k]) + b2f(v1[k])) + (b2f(v2[k]) + b2f(v3[k]));
                }
                for (; j < re; j++) {
                    int s = csr_src[j];
                    bf16x8 v = *(const bf16x8*)(xl + (size_t)s * D);
                    #pragma unroll
                    for (int k = 0; k < 8; k++) acc[k] += b2f(v[k]);
                }
                float rn = rsqrtf((float)max(re - rs, 1));
                union { float4 f4; __hip_bfloat16 h[8]; } o;
                #pragma unroll
                for (int k = 0; k < 8; k++) o.h[k] = __float2bfloat16(acc[k] * rn);
                *(float4*)dst = o.f4;
            } else {
                *(float4*)dst = (float4){0.f, 0.f, 0.f, 0.f};  // zero-fill OOB rows
            }
        }
    }
    __syncthreads();

    // ---- phase 2: GEMM from LDS A + L2 B ----
    int wm = wid >> 2, wn = wid & 3;
    int r0 = wm * 32 + coll;      // tile-local row of A-frag0 (A layout: row = lane&15)
    int r1 = r0 + 16;
    const char* wb = (const char*)Wp + ((size_t)(wn * 128) * 64 + lane) * 16;

    f32x4 acc0[8], acc1[8];
    #pragma unroll
    for (int t = 0; t < 8; t++) { acc0[t] = (f32x4){0,0,0,0}; acc1[t] = (f32x4){0,0,0,0}; }

    for (int kt = 0; kt < 16; kt++) {
        int kb = kt * 64 + l4 * 16;
        bf16x8 af0 = *(const bf16x8*)(ldsA + r0 * 1024 + (kb ^ ((r0 & 7) << 4)));
        bf16x8 af1 = *(const bf16x8*)(ldsA + r1 * 1024 + (kb ^ ((r1 & 7) << 4)));
        const char* wk = wb + (size_t)kt * 8192;
        #pragma unroll
        for (int t = 0; t < 8; t++) {
            bf16x8 bf = *(const bf16x8*)(wk + (size_t)t * 1024);
            acc0[t] = __builtin_amdgcn_mfma_f32_16x16x32_bf16(af0, bf, acc0[t], 0, 0, 0);
            acc1[t] = __builtin_amdgcn_mfma_f32_16x16x32_bf16(af1, bf, acc1[t], 0, 0, 0);
        }
    }

    // ---- epilogue: bias + LN stats + GELU (C layout: row = l4*4+r, col = coll) ----
    float bia[8], gam[8], bet[8];
    #pragma unroll
    for (int t = 0; t < 8; t++) {
        int col = wn * 128 + t * 16 + coll;
        bia[t] = bias[col]; gam[t] = gamma[col]; bet[t] = beta[col];
    }
    #pragma unroll
    for (int ai = 0; ai < 2; ai++) {
        f32x4* acc = ai ? acc1 : acc0;
        #pragma unroll
        for (int r = 0; r < 4; r++) {
            float s = 0.f, q = 0.f;
            #pragma unroll
            for (int t = 0; t < 8; t++) {
                float v = acc[t][r] + bia[t];
                acc[t][r] = v;
                s += v; q += v * v;
            }
            #pragma unroll
            for (int off = 1; off < 16; off <<= 1) {
                s += __shfl_xor(s, off, 64);
                q += __shfl_xor(q, off, 64);
            }
            if (coll == 0) {
                int rb = wm * 32 + ai * 16 + l4 * 4 + r;
                s_sum[rb][wn] = s;
                s_sq[rb][wn] = q;
            }
        }
    }
    __syncthreads();

    #pragma unroll
    for (int ai = 0; ai < 2; ai++) {
        f32x4* acc = ai ? acc1 : acc0;
        #pragma unroll
        for (int r = 0; r < 4; r++) {
            int rb = wm * 32 + ai * 16 + l4 * 4 + r;
            int gr = tb + rb;
            if (gr >= M) continue;
            float s = s_sum[rb][0] + s_sum[rb][1] + s_sum[rb][2] + s_sum[rb][3];
            float q = s_sq[rb][0] + s_sq[rb][1] + s_sq[rb][2] + s_sq[rb][3];
            float mean = s * (1.0f / 512.0f);
            float var = q * (1.0f / 512.0f) - mean * mean;
            float rstd = rsqrtf(fmaxf(var, 0.f) + 1e-5f);
            float* orow = out + (size_t)gr * D + wn * 128 + coll;
            #pragma unroll
            for (int t = 0; t < 8; t++) {
                float y = (acc[t][r] - mean) * rstd * gam[t] + bet[t];
                float yy = y * y;
                float pz = fmaf(yy, -0.1029423374f, -2.3022076728f);
                float e = __builtin_amdgcn_exp2f(y * pz);
                float g = y * __builtin_amdgcn_rcpf(1.0f + e);
                orow[t * 16] = g;
            }
        }
    }
}

// ---------------- legacy fallback kernels (ws too small for xs) ----------------
__global__ __launch_bounds__(256)
void k_spmm_f32(const float* __restrict__ x, const int* __restrict__ row_start,
                const int* __restrict__ csr_src, const int* __restrict__ deg_out,
                __hip_bfloat16* __restrict__ A, int N) {
    int wid = threadIdx.x >> 6;
    int lane = threadIdx.x & 63;
    int node = blockIdx.x * 4 + wid;
    if (node >= N) return;
    int rs = row_start[node], re = row_start[node + 1];
    float4 acc0 = {0.f, 0.f, 0.f, 0.f};
    float4 acc1 = {0.f, 0.f, 0.f, 0.f};
    const float* xl = x + (size_t)lane * 8;
    for (int j = rs; j < re; j++) {
        int s = csr_src[j];
        float w = rsqrtf((float)max(deg_out[s], 1));
        const float4* p = (const float4*)(xl + (size_t)s * D);
        float4 a = p[0], b = p[1];
        acc0.x += a.x * w; acc0.y += a.y * w; acc0.z += a.z * w; acc0.w += a.w * w;
        acc1.x += b.x * w; acc1.y += b.y * w; acc1.z += b.z * w; acc1.w += b.w * w;
    }
    float rn = rsqrtf((float)max(re - rs, 1));
    union { float4 f4; __hip_bfloat16 h[8]; } o;
    o.h[0] = __float2bfloat16(acc0.x * rn);
    o.h[1] = __float2bfloat16(acc0.y * rn);
    o.h[2] = __float2bfloat16(acc0.z * rn);
    o.h[3] = __float2bfloat16(acc0.w * rn);
    o.h[4] = __float2bfloat16(acc1.x * rn);
    o.h[5] = __float2bfloat16(acc1.y * rn);
    o.h[6] = __float2bfloat16(acc1.z * rn);
    o.h[7] = __float2bfloat16(acc1.w * rn);
    *(float4*)(A + (size_t)node * D + lane * 8) = o.f4;
}

__global__ void k_packw(const float* __restrict__ W, __hip_bfloat16* __restrict__ Wp) {
    int tile = blockIdx.x;
    int lane = threadIdx.x;
    int kt = tile >> 5, nt = tile & 31;
    int k0 = kt * 32 + (lane >> 4) * 8;
    int n  = nt * 16 + (lane & 15);
    union { float4 f4; __hip_bfloat16 h[8]; } o;
    #pragma unroll
    for (int j = 0; j < 8; j++)
        o.h[j] = __float2bfloat16(W[(size_t)(k0 + j) * D + n]);
    *(float4*)(Wp + ((size_t)tile * 64 + lane) * 8) = o.f4;
}

__global__ __launch_bounds__(512)
void k_gemm(const __hip_bfloat16* __restrict__ A, const __hip_bfloat16* __restrict__ Wp,
            const float* __restrict__ bias, const float* __restrict__ gamma,
            const float* __restrict__ beta, float* __restrict__ out, int M) {
    int tid = threadIdx.x;
    int wid = tid >> 6, lane = tid & 63;
    int wm = wid >> 2;
    int wn = wid & 3;
    int l4 = lane >> 4, coll = lane & 15;
    int m0 = blockIdx.x * 32 + wm * 16;
    int arow = m0 + coll;
    bool rowok = (arow < M);

    f32x4 acc[8];
    #pragma unroll
    for (int t = 0; t < 8; t++) acc[t] = (f32x4){0.f, 0.f, 0.f, 0.f};

    const bf16x8* wpb = (const bf16x8*)Wp;
    for (int kt = 0; kt < 16; kt++) {
        bf16x8 afrag;
        if (rowok) afrag = *(const bf16x8*)(A + (size_t)arow * D + kt * 32 + l4 * 8);
        else afrag = (bf16x8){0,0,0,0,0,0,0,0};
        const bf16x8* wp = wpb + ((size_t)(kt * 32 + wn * 8) * 64 + lane);
        #pragma unroll
        for (int t = 0; t < 8; t++) {
            bf16x8 bfrag = wp[(size_t)t * 64];
            acc[t] = __builtin_amdgcn_mfma_f32_16x16x32_bf16(afrag, bfrag, acc[t], 0, 0, 0);
        }
    }
    __shared__ float s_sum[32][4];
    __shared__ float s_sq[32][4];
    #pragma unroll
    for (int r = 0; r < 4; r++) {
        float s = 0.f, q = 0.f;
        #pragma unroll
        for (int t = 0; t < 8; t++) {
            int col = wn * 128 + t * 16 + coll;
            float v = acc[t][r] + bias[col];
            acc[t][r] = v;
            s += v; q += v * v;
        }
        #pragma unroll
        for (int off = 1; off < 16; off <<= 1) {
            s += __shfl_xor(s, off, 64);
            q += __shfl_xor(q, off, 64);
        }
        if (coll == 0) {
            int rb = wm * 16 + l4 * 4 + r;
            s_sum[rb][wn] = s;
            s_sq[rb][wn] = q;
        }
    }
    __syncthreads();
    #pragma unroll
    for (int r = 0; r < 4; r++) {
        int rb = wm * 16 + l4 * 4 + r;
        int gr = blockIdx.x * 32 + rb;
        if (gr >= M) continue;
        float s = s_sum[rb][0] + s_sum[rb][1] + s_sum[rb][2] + s_sum[rb][3];
        float q = s_sq[rb][0] + s_sq[rb][1] + s_sq[rb][2] + s_sq[rb][3];
        float mean = s * (1.0f / 512.0f);
        float var = q * (1.0f / 512.0f) - mean * mean;
        float rstd = rsqrtf(fmaxf(var, 0.f) + 1e-5f);
        #pragma unroll
        for (int t = 0; t < 8; t++) {
            int col = wn * 128 + t * 16 + coll;
            float y = (acc[t][r] - mean) * rstd * gamma[col] + beta[col];
            float yy = y * y;
            float pz = fmaf(yy, -0.1029423374f, -2.3022076728f);
            float e = __builtin_amdgcn_exp2f(y * pz);
            out[(size_t)gr * D + col] = y * __builtin_amdgcn_rcpf(1.0f + e);
        }
    }
}

extern "C" void kernel_launch(void* const* d_in, const int* in_sizes, int n_in,
                              void* d_out, int out_size, void* d_ws, size_t ws_size,
                              hipStream_t stream) {
    const float* x     = (const float*)d_in[0];
    const float* W     = (const float*)d_in[1];
    const float* b     = (const float*)d_in[2];
    const float* gamma = (const float*)d_in[3];
    const float* beta  = (const float*)d_in[4];
    const int*   src   = (const int*)d_in[5];
    const int*   dst   = (const int*)d_in[6];
    int N = in_sizes[0] / D;
    int E = in_sizes[5];
    float* out = (float*)d_out;

    int* deg_out   = (int*)d_ws;                 // N
    int* deg_in    = deg_out + N;                // N
    int* row_start = deg_in + N;                 // N+1
    int* cursor    = row_start + N + 1;          // N
    int* partials  = cursor + N;                 // <=64
    int* csr_src   = partials + 64;              // E
    uintptr_t p = (uintptr_t)(csr_src + E);
    p = (p + 255) & ~(uintptr_t)255;
    __hip_bfloat16* A = (__hip_bfloat16*)p;      // N*D bf16 (legacy fallback only)
    p += (size_t)N * D * sizeof(__hip_bfloat16);
    p = (p + 255) & ~(uintptr_t)255;
    __hip_bfloat16* Wp = (__hip_bfloat16*)p;     // D*D bf16
    p += (size_t)D * D * sizeof(__hip_bfloat16);
    p = (p + 255) & ~(uintptr_t)255;
    __hip_bfloat16* xs = (__hip_bfloat16*)p;     // N*D bf16
    size_t need_xs = (p - (uintptr_t)d_ws) + (size_t)N * D * sizeof(__hip_bfloat16);
    bool use_bf16_path = (ws_size >= need_xs);

    hipMemsetAsync(deg_out, 0, (size_t)2 * N * sizeof(int), stream);
    hipMemsetAsync(cursor, 0, (size_t)N * sizeof(int), stream);

    k_hist<<<(E + 255) / 256, 256, 0, stream>>>(src, dst, deg_out, deg_in, E);
    int nb1 = (N + 1023) / 1024;
    k_scan1<<<nb1, 1024, 0, stream>>>(deg_in, row_start, partials, N);
    if (nb1 <= 64)
        k_scan2w<<<1, 64, 0, stream>>>(partials, row_start, nb1, N);
    else
        k_scan2s<<<1, 64, 0, stream>>>(partials, row_start, nb1, N);
    k_scan3<<<(N + 255) / 256, 256, 0, stream>>>(row_start, partials, N);
    k_fill<<<(E + 255) / 256, 256, 0, stream>>>(src, dst, row_start, cursor, csr_src, E);

    if (use_bf16_path) {
        int total16 = N * 64;
        k_scale<<<(total16 + 255) / 256, 256, 0, stream>>>(x, deg_out, xs, total16);
        k_packw2<<<512, 64, 0, stream>>>(W, Wp);
        k_fused<<<(N + 63) / 64, 512, 0, stream>>>(xs, row_start, csr_src, Wp,
                                                   b, gamma, beta, out, N);
    } else {
        k_spmm_f32<<<(N + 3) / 4, 256, 0, stream>>>(x, row_start, csr_src, deg_out, A, N);
        k_packw<<<512, 64, 0, stream>>>(W, Wp);
        k_gemm<<<(N + 31) / 32, 512, 0, stream>>>(A, Wp, b, gamma, beta, out, N);
    }
}

// Round 10
// 251.474 us; speedup vs baseline: 2.8187x; 1.1588x over previous
//
#include <hip/hip_runtime.h>
#include <hip/hip_bf16.h>

#define D 512

typedef __attribute__((ext_vector_type(8))) short bf16x8;
typedef __attribute__((ext_vector_type(4))) float f32x4;

__device__ inline float b2f(short h) {
    union { unsigned u; float f; } c;
    c.u = ((unsigned)(unsigned short)h) << 16;
    return c.f;
}

// ---------------- degree histograms ----------------
__global__ void k_hist(const int* __restrict__ src, const int* __restrict__ dst,
                       int* __restrict__ deg_out, int* __restrict__ deg_in, int E) {
    int e = blockIdx.x * 256 + threadIdx.x;
    if (e < E) {
        atomicAdd(&deg_out[src[e]], 1);
        atomicAdd(&deg_in[dst[e]], 1);
    }
}

// ---------------- exclusive scan of deg_in -> row_start ----------------
__global__ void k_scan1(const int* __restrict__ deg_in, int* __restrict__ row_start,
                        int* __restrict__ partials, int N) {
    __shared__ int sm[1024];
    int tid = threadIdx.x;
    int i = blockIdx.x * 1024 + tid;
    int v = (i < N) ? deg_in[i] : 0;
    sm[tid] = v;
    __syncthreads();
    int acc = v;
    #pragma unroll
    for (int off = 1; off < 1024; off <<= 1) {
        int t = (tid >= off) ? sm[tid - off] : 0;
        __syncthreads();
        acc += t;
        sm[tid] = acc;
        __syncthreads();
    }
    if (i < N) row_start[i] = acc - v;
    if (tid == 1023) partials[blockIdx.x] = acc;
}

__global__ void k_scan2w(int* __restrict__ partials, int* __restrict__ row_start,
                         int nb, int N) {
    int lane = threadIdx.x;
    int orig = (lane < nb) ? partials[lane] : 0;
    int v = orig;
    #pragma unroll
    for (int off = 1; off < 64; off <<= 1) {
        int t = __shfl_up(v, off, 64);
        if (lane >= off) v += t;
    }
    if (lane < nb) partials[lane] = v - orig;
    if (lane == 63) row_start[N] = v;
}

__global__ void k_scan2s(int* __restrict__ partials, int* __restrict__ row_start,
                         int nb, int N) {
    if (threadIdx.x == 0 && blockIdx.x == 0) {
        int run = 0;
        for (int b = 0; b < nb; b++) { int t = partials[b]; partials[b] = run; run += t; }
        row_start[N] = run;
    }
}

__global__ void k_scan3(int* __restrict__ row_start, const int* __restrict__ partials, int N) {
    int i = blockIdx.x * 256 + threadIdx.x;
    if (i < N) row_start[i] += partials[i >> 10];
}

// ---------------- CSR bucket fill ----------------
__global__ void k_fill(const int* __restrict__ src, const int* __restrict__ dst,
                       const int* __restrict__ row_start, int* __restrict__ cursor,
                       int* __restrict__ csr_src, int E) {
    int e = blockIdx.x * 256 + threadIdx.x;
    if (e < E) {
        int d = dst[e];
        int slot = atomicAdd(&cursor[d], 1);
        csr_src[row_start[d] + slot] = src[e];
    }
}

// ---------------- pack W into per-col-chunk MFMA B layout ----------------
// bid = c*128 + kt*8 + ntc ; element (bid, lane, j) =
//   W[kt*32 + (lane>>4)*8 + j][(c*8 + ntc)*16 + (lane&15)]
__global__ void k_packw2(const float* __restrict__ W, __hip_bfloat16* __restrict__ Wp) {
    int bid = blockIdx.x;        // 0..511
    int c = bid >> 7, kt = (bid >> 3) & 15, ntc = bid & 7;
    int lane = threadIdx.x;      // 0..63
    int k0 = kt * 32 + (lane >> 4) * 8;
    int n  = (c * 8 + ntc) * 16 + (lane & 15);
    union { float4 f4; __hip_bfloat16 h[8]; } o;
    #pragma unroll
    for (int j = 0; j < 8; j++)
        o.h[j] = __float2bfloat16(W[(size_t)(k0 + j) * D + n]);
    *(float4*)(Wp + ((size_t)bid * 64 + lane) * 8) = o.f4;
}

// ---------------- pass A: y = diag(rsqrt(deg_out)) * x * W  (bf16 y) ----------------
// 64-row x 512-col blocks, 8 waves (wm = wid>>2, wn = wid&3), no K-loop barriers.
// A-frags: read x f32 directly (32B/lane), convert to bf16 in-register.
// B-frags: register-direct 1KB loads from L2-resident packed Wp.
// Epilogue: scale acc rows by rsqrt(deg_out[row]); bf16 convert; XOR-swizzled LDS
// repack ([64][1KB], byte ^= (row&7)<<4 at 16B granule); coalesced 1KB/wave stores.
__global__ __launch_bounds__(512, 2)
void k_gemmY(const float* __restrict__ x, const __hip_bfloat16* __restrict__ Wp,
             const int* __restrict__ deg_out, __hip_bfloat16* __restrict__ y, int M) {
    __shared__ __align__(16) char ldsY[65536];

    int tid = threadIdx.x;
    int wid = tid >> 6, lane = tid & 63;
    int wm = wid >> 2, wn = wid & 3;
    int l4 = lane >> 4, coll = lane & 15;
    int tb = blockIdx.x * 64;

    int r0 = wm * 32 + coll;          // tile-local A row of frag0
    int r1 = r0 + 16;
    int grA = min(tb + r0, M - 1);    // clamp: dup rows never stored
    int grB = min(tb + r1, M - 1);
    const float* xa = x + (size_t)grA * D + l4 * 8;
    const float* xb = x + (size_t)grB * D + l4 * 8;
    const char* wb = (const char*)Wp + ((size_t)(wn * 128) * 64 + lane) * 16;

    f32x4 acc0[8], acc1[8];
    #pragma unroll
    for (int t = 0; t < 8; t++) { acc0[t] = (f32x4){0,0,0,0}; acc1[t] = (f32x4){0,0,0,0}; }

    for (int kt = 0; kt < 16; kt++) {
        const float4* pa = (const float4*)(xa + kt * 32);
        const float4* pb = (const float4*)(xb + kt * 32);
        float4 a0 = pa[0], a1 = pa[1];
        float4 b0 = pb[0], b1 = pb[1];
        union { bf16x8 v; __hip_bfloat16 h[8]; } ua, ub;
        ua.h[0] = __float2bfloat16(a0.x); ua.h[1] = __float2bfloat16(a0.y);
        ua.h[2] = __float2bfloat16(a0.z); ua.h[3] = __float2bfloat16(a0.w);
        ua.h[4] = __float2bfloat16(a1.x); ua.h[5] = __float2bfloat16(a1.y);
        ua.h[6] = __float2bfloat16(a1.z); ua.h[7] = __float2bfloat16(a1.w);
        ub.h[0] = __float2bfloat16(b0.x); ub.h[1] = __float2bfloat16(b0.y);
        ub.h[2] = __float2bfloat16(b0.z); ub.h[3] = __float2bfloat16(b0.w);
        ub.h[4] = __float2bfloat16(b1.x); ub.h[5] = __float2bfloat16(b1.y);
        ub.h[6] = __float2bfloat16(b1.z); ub.h[7] = __float2bfloat16(b1.w);
        const char* wk = wb + (size_t)kt * 8192;
        #pragma unroll
        for (int t = 0; t < 8; t++) {
            bf16x8 bf = *(const bf16x8*)(wk + (size_t)t * 1024);
            acc0[t] = __builtin_amdgcn_mfma_f32_16x16x32_bf16(ua.v, bf, acc0[t], 0, 0, 0);
            acc1[t] = __builtin_amdgcn_mfma_f32_16x16x32_bf16(ub.v, bf, acc1[t], 0, 0, 0);
        }
    }

    // epilogue: per-row deg_out scale, bf16, swizzled LDS
    #pragma unroll
    for (int ai = 0; ai < 2; ai++) {
        f32x4* acc = ai ? acc1 : acc0;
        #pragma unroll
        for (int r = 0; r < 4; r++) {
            int rt = wm * 32 + ai * 16 + l4 * 4 + r;       // tile-local C row
            int grow = min(tb + rt, M - 1);
            float wv = rsqrtf((float)max(deg_out[grow], 1));
            int xorv = (rt & 7) << 4;
            char* rowp = ldsY + rt * 1024;
            #pragma unroll
            for (int t = 0; t < 8; t++) {
                int col = wn * 128 + t * 16 + coll;
                *(__hip_bfloat16*)(rowp + ((col * 2) ^ xorv)) =
                    __float2bfloat16(acc[t][r] * wv);
            }
        }
    }
    __syncthreads();

    // coalesced copy-out: 8 rounds x 512 thr x 16B; wave = one full 1KB row
    #pragma unroll
    for (int i = 0; i < 8; i++) {
        int chunk = i * 512 + tid;        // 0..4095
        int row = chunk >> 6;             // 64 chunks per row
        int cc = chunk & 63;
        int grow = tb + row;
        if (grow < M) {
            float4 v = *(const float4*)(ldsY + row * 1024 + ((cc * 16) ^ ((row & 7) << 4)));
            *(float4*)((char*)y + (size_t)grow * 1024 + cc * 16) = v;
        }
    }
}

// ---------------- pass B: gather y rows + deg_in norm + bias + LN + GELU ----------------
// One wave per dst node (proven 62us spmm loop); full row in registers (8 f32/lane),
// LN stats via shfl_xor over 64 lanes; coalesced 32B/lane f32 stores.
__global__ __launch_bounds__(256)
void k_gather(const __hip_bfloat16* __restrict__ y, const int* __restrict__ row_start,
              const int* __restrict__ csr_src, const float* __restrict__ bias,
              const float* __restrict__ gamma, const float* __restrict__ beta,
              float* __restrict__ out, int N) {
    int wid = threadIdx.x >> 6;
    int lane = threadIdx.x & 63;
    int node = blockIdx.x * 4 + wid;
    if (node >= N) return;
    int rs = row_start[node], re = row_start[node + 1];

    float bi8[8], g8[8], b8[8];
    #pragma unroll
    for (int k = 0; k < 8; k++) {
        bi8[k] = bias[lane * 8 + k];
        g8[k] = gamma[lane * 8 + k];
        b8[k] = beta[lane * 8 + k];
    }

    float acc[8];
    #pragma unroll
    for (int k = 0; k < 8; k++) acc[k] = 0.f;
    const __hip_bfloat16* yl = y + (size_t)lane * 8;

    int j = rs;
    for (; j + 4 <= re; j += 4) {
        int s0 = csr_src[j], s1 = csr_src[j + 1], s2 = csr_src[j + 2], s3 = csr_src[j + 3];
        bf16x8 v0 = *(const bf16x8*)(yl + (size_t)s0 * D);
        bf16x8 v1 = *(const bf16x8*)(yl + (size_t)s1 * D);
        bf16x8 v2 = *(const bf16x8*)(yl + (size_t)s2 * D);
        bf16x8 v3 = *(const bf16x8*)(yl + (size_t)s3 * D);
        #pragma unroll
        for (int k = 0; k < 8; k++)
            acc[k] += (b2f(v0[k]) + b2f(v1[k])) + (b2f(v2[k]) + b2f(v3[k]));
    }
    for (; j < re; j++) {
        int s = csr_src[j];
        bf16x8 v = *(const bf16x8*)(yl + (size_t)s * D);
        #pragma unroll
        for (int k = 0; k < 8; k++) acc[k] += b2f(v[k]);
    }

    float rn = rsqrtf((float)max(re - rs, 1));
    float f[8];
    float s = 0.f, q = 0.f;
    #pragma unroll
    for (int k = 0; k < 8; k++) {
        f[k] = acc[k] * rn + bi8[k];
        s += f[k]; q += f[k] * f[k];
    }
    #pragma unroll
    for (int off = 1; off < 64; off <<= 1) {
        s += __shfl_xor(s, off, 64);
        q += __shfl_xor(q, off, 64);
    }
    float mean = s * (1.0f / 512.0f);
    float var = q * (1.0f / 512.0f) - mean * mean;
    float rstd = rsqrtf(fmaxf(var, 0.f) + 1e-5f);
    float o[8];
    #pragma unroll
    for (int k = 0; k < 8; k++) {
        float yv = (f[k] - mean) * rstd * g8[k] + b8[k];
        float yy = yv * yv;
        float pz = fmaf(yy, -0.1029423374f, -2.3022076728f);
        float e = __builtin_amdgcn_exp2f(yv * pz);
        o[k] = yv * __builtin_amdgcn_rcpf(1.0f + e);
    }
    float* orow = out + (size_t)node * D + lane * 8;
    *(float4*)orow = (float4){o[0], o[1], o[2], o[3]};
    *(float4*)(orow + 4) = (float4){o[4], o[5], o[6], o[7]};
}

// ---------------- legacy fallback kernels (ws too small) ----------------
__global__ __launch_bounds__(256)
void k_spmm_f32(const float* __restrict__ x, const int* __restrict__ row_start,
                const int* __restrict__ csr_src, const int* __restrict__ deg_out,
                __hip_bfloat16* __restrict__ A, int N) {
    int wid = threadIdx.x >> 6;
    int lane = threadIdx.x & 63;
    int node = blockIdx.x * 4 + wid;
    if (node >= N) return;
    int rs = row_start[node], re = row_start[node + 1];
    float4 acc0 = {0.f, 0.f, 0.f, 0.f};
    float4 acc1 = {0.f, 0.f, 0.f, 0.f};
    const float* xl = x + (size_t)lane * 8;
    for (int j = rs; j < re; j++) {
        int s = csr_src[j];
        float w = rsqrtf((float)max(deg_out[s], 1));
        const float4* p = (const float4*)(xl + (size_t)s * D);
        float4 a = p[0], b = p[1];
        acc0.x += a.x * w; acc0.y += a.y * w; acc0.z += a.z * w; acc0.w += a.w * w;
        acc1.x += b.x * w; acc1.y += b.y * w; acc1.z += b.z * w; acc1.w += b.w * w;
    }
    float rn = rsqrtf((float)max(re - rs, 1));
    union { float4 f4; __hip_bfloat16 h[8]; } o;
    o.h[0] = __float2bfloat16(acc0.x * rn);
    o.h[1] = __float2bfloat16(acc0.y * rn);
    o.h[2] = __float2bfloat16(acc0.z * rn);
    o.h[3] = __float2bfloat16(acc0.w * rn);
    o.h[4] = __float2bfloat16(acc1.x * rn);
    o.h[5] = __float2bfloat16(acc1.y * rn);
    o.h[6] = __float2bfloat16(acc1.z * rn);
    o.h[7] = __float2bfloat16(acc1.w * rn);
    *(float4*)(A + (size_t)node * D + lane * 8) = o.f4;
}

__global__ void k_packw(const float* __restrict__ W, __hip_bfloat16* __restrict__ Wp) {
    int tile = blockIdx.x;
    int lane = threadIdx.x;
    int kt = tile >> 5, nt = tile & 31;
    int k0 = kt * 32 + (lane >> 4) * 8;
    int n  = nt * 16 + (lane & 15);
    union { float4 f4; __hip_bfloat16 h[8]; } o;
    #pragma unroll
    for (int j = 0; j < 8; j++)
        o.h[j] = __float2bfloat16(W[(size_t)(k0 + j) * D + n]);
    *(float4*)(Wp + ((size_t)tile * 64 + lane) * 8) = o.f4;
}

__global__ __launch_bounds__(512)
void k_gemm(const __hip_bfloat16* __restrict__ A, const __hip_bfloat16* __restrict__ Wp,
            const float* __restrict__ bias, const float* __restrict__ gamma,
            const float* __restrict__ beta, float* __restrict__ out, int M) {
    int tid = threadIdx.x;
    int wid = tid >> 6, lane = tid & 63;
    int wm = wid >> 2;
    int wn = wid & 3;
    int l4 = lane >> 4, coll = lane & 15;
    int m0 = blockIdx.x * 32 + wm * 16;
    int arow = m0 + coll;
    bool rowok = (arow < M);

    f32x4 acc[8];
    #pragma unroll
    for (int t = 0; t < 8; t++) acc[t] = (f32x4){0.f, 0.f, 0.f, 0.f};

    const bf16x8* wpb = (const bf16x8*)Wp;
    for (int kt = 0; kt < 16; kt++) {
        bf16x8 afrag;
        if (rowok) afrag = *(const bf16x8*)(A + (size_t)arow * D + kt * 32 + l4 * 8);
        else afrag = (bf16x8){0,0,0,0,0,0,0,0};
        const bf16x8* wp = wpb + ((size_t)(kt * 32 + wn * 8) * 64 + lane);
        #pragma unroll
        for (int t = 0; t < 8; t++) {
            bf16x8 bfrag = wp[(size_t)t * 64];
            acc[t] = __builtin_amdgcn_mfma_f32_16x16x32_bf16(afrag, bfrag, acc[t], 0, 0, 0);
        }
    }
    __shared__ float s_sum[32][4];
    __shared__ float s_sq[32][4];
    #pragma unroll
    for (int r = 0; r < 4; r++) {
        float s = 0.f, q = 0.f;
        #pragma unroll
        for (int t = 0; t < 8; t++) {
            int col = wn * 128 + t * 16 + coll;
            float v = acc[t][r] + bias[col];
            acc[t][r] = v;
            s += v; q += v * v;
        }
        #pragma unroll
        for (int off = 1; off < 16; off <<= 1) {
            s += __shfl_xor(s, off, 64);
            q += __shfl_xor(q, off, 64);
        }
        if (coll == 0) {
            int rb = wm * 16 + l4 * 4 + r;
            s_sum[rb][wn] = s;
            s_sq[rb][wn] = q;
        }
    }
    __syncthreads();
    #pragma unroll
    for (int r = 0; r < 4; r++) {
        int rb = wm * 16 + l4 * 4 + r;
        int gr = blockIdx.x * 32 + rb;
        if (gr >= M) continue;
        float s = s_sum[rb][0] + s_sum[rb][1] + s_sum[rb][2] + s_sum[rb][3];
        float q = s_sq[rb][0] + s_sq[rb][1] + s_sq[rb][2] + s_sq[rb][3];
        float mean = s * (1.0f / 512.0f);
        float var = q * (1.0f / 512.0f) - mean * mean;
        float rstd = rsqrtf(fmaxf(var, 0.f) + 1e-5f);
        #pragma unroll
        for (int t = 0; t < 8; t++) {
            int col = wn * 128 + t * 16 + coll;
            float y = (acc[t][r] - mean) * rstd * gamma[col] + beta[col];
            float yy = y * y;
            float pz = fmaf(yy, -0.1029423374f, -2.3022076728f);
            float e = __builtin_amdgcn_exp2f(y * pz);
            out[(size_t)gr * D + col] = y * __builtin_amdgcn_rcpf(1.0f + e);
        }
    }
}

extern "C" void kernel_launch(void* const* d_in, const int* in_sizes, int n_in,
                              void* d_out, int out_size, void* d_ws, size_t ws_size,
                              hipStream_t stream) {
    const float* x     = (const float*)d_in[0];
    const float* W     = (const float*)d_in[1];
    const float* b     = (const float*)d_in[2];
    const float* gamma = (const float*)d_in[3];
    const float* beta  = (const float*)d_in[4];
    const int*   src   = (const int*)d_in[5];
    const int*   dst   = (const int*)d_in[6];
    int N = in_sizes[0] / D;
    int E = in_sizes[5];
    float* out = (float*)d_out;

    int* deg_out   = (int*)d_ws;                 // N
    int* deg_in    = deg_out + N;                // N
    int* row_start = deg_in + N;                 // N+1
    int* cursor    = row_start + N + 1;          // N
    int* partials  = cursor + N;                 // <=64
    int* csr_src   = partials + 64;              // E
    uintptr_t p = (uintptr_t)(csr_src + E);
    p = (p + 255) & ~(uintptr_t)255;
    __hip_bfloat16* y = (__hip_bfloat16*)p;      // N*D bf16 (y = x*W scaled; legacy: A)
    p += (size_t)N * D * sizeof(__hip_bfloat16);
    p = (p + 255) & ~(uintptr_t)255;
    __hip_bfloat16* Wp = (__hip_bfloat16*)p;     // D*D bf16
    size_t need = (p - (uintptr_t)d_ws) + (size_t)D * D * sizeof(__hip_bfloat16);
    bool main_path = (ws_size >= need);

    hipMemsetAsync(deg_out, 0, (size_t)2 * N * sizeof(int), stream);
    hipMemsetAsync(cursor, 0, (size_t)N * sizeof(int), stream);

    k_hist<<<(E + 255) / 256, 256, 0, stream>>>(src, dst, deg_out, deg_in, E);
    int nb1 = (N + 1023) / 1024;
    k_scan1<<<nb1, 1024, 0, stream>>>(deg_in, row_start, partials, N);
    if (nb1 <= 64)
        k_scan2w<<<1, 64, 0, stream>>>(partials, row_start, nb1, N);
    else
        k_scan2s<<<1, 64, 0, stream>>>(partials, row_start, nb1, N);
    k_scan3<<<(N + 255) / 256, 256, 0, stream>>>(row_start, partials, N);
    k_fill<<<(E + 255) / 256, 256, 0, stream>>>(src, dst, row_start, cursor, csr_src, E);

    if (main_path) {
        k_packw2<<<512, 64, 0, stream>>>(W, Wp);
        k_gemmY<<<(N + 63) / 64, 512, 0, stream>>>(x, Wp, deg_out, y, N);
        k_gather<<<(N + 3) / 4, 256, 0, stream>>>(y, row_start, csr_src, b, gamma, beta, out, N);
    } else {
        k_spmm_f32<<<(N + 3) / 4, 256, 0, stream>>>(x, row_start, csr_src, deg_out, y, N);
        k_packw<<<512, 64, 0, stream>>>(W, Wp);
        k_gemm<<<(N + 31) / 32, 512, 0, stream>>>(y, Wp, b, gamma, beta, out, N);
    }
}